// Round 1
// baseline (324.927 us; speedup 1.0000x reference)
//
#include <hip/hip_runtime.h>
#include <hip/hip_bf16.h>

// Complex ConvLSTM cell. Inputs f32, output f32 (verified R3, absmax 0.0625).
//   Zp: halo-padded packed activations, [b][y' 0..65][x' 0..65][cin 0..255] bf16
//       cin = [x lo | h lo | x hi | h hi]; halo = zeros.
//   Wp[n][tap][cin]: n = part*64+ch, parts {yr_i,yi_i,yr_o,yi_o,yr_c,yi_c};
//       yr -> [Wr ; -Wi], yi -> [Wi ; Wr].
//   conv_gemm: 128ch x 128px block tile, global_load_lds(16B) staging,
//       XOR-swizzled LDS k-groups, dy-grouped taps (B staged once per 3 dx).
//   epilogue: gate math -> h_new, c_new (f32). R1: vectorized 8 px/thread
//       (short8 gate loads, float4 x/c/out) — was scalar 2-4B/lane.

typedef __attribute__((ext_vector_type(8))) short short8;
typedef __attribute__((ext_vector_type(4))) float floatx4;
typedef __attribute__((ext_vector_type(4))) float float4v;

#define MTOT   65536
#define HSIZE  8388608
#define ZP_ELEMS (16 * 66 * 66 * 256)          // 17,842,176 shorts

__device__ __forceinline__ short f2bf(float f) {
  __hip_bfloat16 h = __float2bfloat16(f);
  return *reinterpret_cast<short*>(&h);
}

__device__ __forceinline__ float bf2f(short s) {
  unsigned u = ((unsigned)(unsigned short)s) << 16;
  return __uint_as_float(u);
}

__device__ __forceinline__ void gload16(const short* g, void* lds) {
  __builtin_amdgcn_global_load_lds(
      (__attribute__((address_space(1))) void*)(g),
      (__attribute__((address_space(3))) void*)(lds), 16, 0, 0);
}

// ---------------------------------------------------------------- halo zero
__global__ __launch_bounds__(256) void halo_zero_kernel(short* __restrict__ Zp) {
  int t = blockIdx.x * 256 + threadIdx.x;     // 520*256 = 133,120 = 4160 px * 32
  int s   = t & 31;
  int pix = t >> 5;                           // 0..4159
  int b = pix / 260;
  int r = pix - b * 260;
  int yp, xp;
  if (r < 66)       { yp = 0;               xp = r; }
  else if (r < 132) { yp = 65;              xp = r - 66; }
  else { int r2 = r - 132; yp = 1 + (r2 >> 1); xp = (r2 & 1) * 65; }
  short8 z;
#pragma unroll
  for (int q = 0; q < 8; ++q) z[q] = 0;
  *(short8*)(Zp + (((b * 66 + yp) * 66 + xp) * 256 + s * 8)) = z;
}

// ---------------------------------------------------------------- pack Z (tiled transpose)
// block: one (b, srcSel, half, y) -> 64ch x 64x tile
__global__ __launch_bounds__(256) void pack_z_kernel(
    const float* __restrict__ xs, const float* __restrict__ hs,
    short* __restrict__ Zp) {
  __shared__ short tile[64 * 72];             // [xr][ch], stride 72 (16B-aligned rows)
  int bid = blockIdx.x;
  int y      = bid & 63;
  int half   = (bid >> 6) & 1;
  int srcSel = (bid >> 7) & 1;
  int b      = bid >> 8;
  const float* src = srcSel ? hs : xs;
  int chBase  = half * 64;
  int cinBase = half * 128 + srcSel * 64;
  int t = threadIdx.x;
  int x4 = t & 15, chq = t >> 4;              // 16 ch per pass
#pragma unroll
  for (int p = 0; p < 4; ++p) {
    int ch = p * 16 + chq;
    float4v f = *(const float4v*)(src + (size_t)(b * 128 + chBase + ch) * 4096 + y * 64 + x4 * 4);
#pragma unroll
    for (int e = 0; e < 4; ++e)
      tile[(x4 * 4 + e) * 72 + ch] = f2bf(f[e]);
  }
  __syncthreads();
  int x = t >> 2, seg = t & 3;
  short8 v0 = *(const short8*)(tile + x * 72 + seg * 16);
  short8 v1 = *(const short8*)(tile + x * 72 + seg * 16 + 8);
  size_t outp = ((size_t)(b * 66 + y + 1) * 66 + x + 1) * 256 + cinBase + seg * 16;
  *(short8*)(Zp + outp)     = v0;
  *(short8*)(Zp + outp + 8) = v1;
}

// ---------------------------------------------------------------- pack W + bias
__global__ __launch_bounds__(256) void pack_w_kernel(
    const float* __restrict__ Wr_i, const float* __restrict__ Wi_i,
    const float* __restrict__ Wr_o, const float* __restrict__ Wi_o,
    const float* __restrict__ Wr_c, const float* __restrict__ Wi_c,
    const float* __restrict__ br_i, const float* __restrict__ bi_i,
    const float* __restrict__ br_o, const float* __restrict__ bi_o,
    const float* __restrict__ br_c, const float* __restrict__ bi_c,
    short* __restrict__ Wp, float* __restrict__ bias) {
  int g = blockIdx.x * 256 + threadIdx.x;
  if (g >= 384 * 9 * 256) return;
  int cin = g & 255;
  int tap = (g >> 8) % 9;
  int n   = g / (256 * 9);
  int part = n >> 6, ch = n & 63;
  const float *Wr, *Wi;
  if (part < 2)      { Wr = Wr_i; Wi = Wi_i; }
  else if (part < 4) { Wr = Wr_o; Wi = Wi_o; }
  else               { Wr = Wr_c; Wi = Wi_c; }
  int im = part & 1;
  int ci = cin & 127;
  int second = cin >> 7;
  const float* src = im ? (second ? Wr : Wi) : (second ? Wi : Wr);
  float f = src[(ch * 128 + ci) * 9 + tap];
  if (!im && second) f = -f;
  Wp[(n * 9 + tap) * 256 + cin] = f2bf(f);
  if (g < 384) {
    int p2 = g >> 6, c2 = g & 63;
    const float* bs = (p2 == 0) ? br_i : (p2 == 1) ? bi_i : (p2 == 2) ? br_o
                    : (p2 == 3) ? bi_o : (p2 == 4) ? br_c : bi_c;
    bias[g] = bs[c2];
  }
}

// ---------------------------------------------------------------- implicit GEMM
// 128ch x 128px tile, 4 waves (each 64x64), K = 9 taps x 256 cin.
// LDS: As[row 0..127][slot 0..7] 16B slots, slot p holds logical k-group p^(row&7).
//      Bs[r2 0..1][col 0..65][slot 0..7], slot p holds logical group p^(col&7).
// Staged via global_load_lds (dest = wave base + lane*16, lane-contiguous).
__global__ __launch_bounds__(256, 3) void conv_gemm(
    const short* __restrict__ Z, const short* __restrict__ Wp,
    const float* __restrict__ bias, __hip_bfloat16* __restrict__ gates) {
  __shared__ short8 As[1024];   // 16 KiB
  __shared__ short8 Bs[1056];   // 16.5 KiB

  const int tid = threadIdx.x;
  const int wv = tid >> 6, lane = tid & 63;
  const int l15 = lane & 15, l4 = lane >> 4;
  const int m0 = blockIdx.x * 128;
  const int n0 = blockIdx.y * 128;
  const int b  = m0 >> 12;
  const int y0 = (m0 >> 6) & 63;    // even
  const int wch = (wv & 1) * 64;    // wave channel offset
  const int r2w = wv >> 1;          // wave pixel-row (0/1) within tile

  floatx4 acc[4][4];
#pragma unroll
  for (int i = 0; i < 4; ++i)
#pragma unroll
    for (int j = 0; j < 4; ++j)
#pragma unroll
      for (int r = 0; r < 4; ++r) acc[i][j][r] = 0.f;

  for (int dy = -1; dy <= 1; ++dy) {
    for (int c0 = 0; c0 < 256; c0 += 64) {
      // ---- stage B: rows y0+dy, y0+1+dy; cols -1..64 (halo-padded Z) ----
#pragma unroll
      for (int it = 0; it < 5; ++it) {
        int idx = tid + it * 256;
        if (idx < 1056) {
          int r2  = (idx >= 528) ? 1 : 0;
          int rem = idx - r2 * 528;
          int col = rem >> 3, p = rem & 7;
          int g   = p ^ (col & 7);
          int ygl = b * 66 + y0 + dy + 1 + r2;
          gload16(Z + ((size_t)(ygl * 66 + col) * 256 + c0 + g * 8),
                  (void*)(Bs + (it * 256 + wv * 64)));
        }
      }
      for (int dx = -1; dx <= 1; ++dx) {
        int tap = (dy + 1) * 3 + (dx + 1);
        // ---- stage A: 128 rows x 64 k ----
#pragma unroll
        for (int it = 0; it < 4; ++it) {
          int idx = tid + it * 256;
          int row = idx >> 3, p = idx & 7;
          int g   = p ^ (row & 7);
          gload16(Wp + ((size_t)((n0 + row) * 9 + tap) * 256 + c0 + g * 8),
                  (void*)(As + (it * 256 + wv * 64)));
        }
        __syncthreads();   // drains vmcnt(0): A + (first iter) B visible
#pragma unroll
        for (int kk = 0; kk < 2; ++kk) {
          int kg = kk * 4 + l4;
          short8 a[4], bf[4];
#pragma unroll
          for (int i = 0; i < 4; ++i) {
            int row = wch + i * 16 + l15;
            a[i] = As[row * 8 + (kg ^ (row & 7))];
          }
#pragma unroll
          for (int j = 0; j < 4; ++j) {
            int col = j * 16 + l15 + dx + 1;
            bf[j] = Bs[r2w * 528 + col * 8 + (kg ^ (col & 7))];
          }
#pragma unroll
          for (int i = 0; i < 4; ++i)
#pragma unroll
            for (int j = 0; j < 4; ++j)
              acc[i][j] = __builtin_amdgcn_mfma_f32_16x16x32_bf16(a[i], bf[j], acc[i][j], 0, 0, 0);
        }
        __syncthreads();   // As (and Bs at dx==1) free for restage
      }
    }
  }
#pragma unroll
  for (int i = 0; i < 4; ++i)
#pragma unroll
    for (int j = 0; j < 4; ++j)
#pragma unroll
      for (int r = 0; r < 4; ++r) {
        int ch = n0 + wch + i * 16 + l4 * 4 + r;
        int px = m0 + r2w * 64 + j * 16 + l15;
        gates[(size_t)ch * MTOT + px] = __float2bfloat16(acc[i][j][r] + bias[ch]);
      }
}

// ---------------------------------------------------------------- epilogue (f32 out)
// R1: 8 px/thread, all accesses 8-16B/lane. 2048 blocks x 256 threads.
__device__ __forceinline__ float fsig(float v) { return 1.f / (1.f + __expf(-v)); }
__device__ __forceinline__ float ftanh(float v) {
  float e = __expf(2.f * v);
  return 1.f - 2.f / (e + 1.f);
}

__global__ __launch_bounds__(256) void epilogue_kernel(
    const __hip_bfloat16* __restrict__ gates,
    const float* __restrict__ x,
    const float* __restrict__ c_prev,
    float* __restrict__ out) {
  int t = blockIdx.x * 256 + threadIdx.x;     // 524,288 threads total
  int ch = t >> 13;                           // 0..63
  int m  = (t & 8191) << 3;                   // 8 consecutive pixels
  int b = m >> 12, sp = m & 4095;

  size_t gbase = (size_t)ch * MTOT + m;
  short8 gri = *(const short8*)((const short*)gates + gbase);
  short8 gii = *(const short8*)((const short*)gates + gbase + (size_t)64 * MTOT);
  short8 gro = *(const short8*)((const short*)gates + gbase + (size_t)128 * MTOT);
  short8 gio = *(const short8*)((const short*)gates + gbase + (size_t)192 * MTOT);
  short8 grc = *(const short8*)((const short*)gates + gbase + (size_t)256 * MTOT);
  short8 gic = *(const short8*)((const short*)gates + gbase + (size_t)320 * MTOT);

  int base = (b * 128 + ch) * 4096 + sp;
  float xr[8] __attribute__((aligned(16)));
  float xi[8] __attribute__((aligned(16)));
  float cr[8] __attribute__((aligned(16)));
  float ci[8] __attribute__((aligned(16)));
  *(float4v*)(xr)     = *(const float4v*)(x + base);
  *(float4v*)(xr + 4) = *(const float4v*)(x + base + 4);
  *(float4v*)(xi)     = *(const float4v*)(x + base + 64 * 4096);
  *(float4v*)(xi + 4) = *(const float4v*)(x + base + 64 * 4096 + 4);
  *(float4v*)(cr)     = *(const float4v*)(c_prev + base);
  *(float4v*)(cr + 4) = *(const float4v*)(c_prev + base + 4);
  *(float4v*)(ci)     = *(const float4v*)(c_prev + base + 64 * 4096);
  *(float4v*)(ci + 4) = *(const float4v*)(c_prev + base + 64 * 4096 + 4);

  float hr[8] __attribute__((aligned(16)));
  float hi[8] __attribute__((aligned(16)));
  float nr[8] __attribute__((aligned(16)));
  float ni[8] __attribute__((aligned(16)));
#pragma unroll
  for (int q = 0; q < 8; ++q) {
    float i_r = fsig(bf2f(gri[q])), i_i = fsig(bf2f(gii[q]));
    float o_r = fsig(bf2f(gro[q])), o_i = fsig(bf2f(gio[q]));
    float ct_r = ftanh(bf2f(grc[q])), ct_i = ftanh(bf2f(gic[q]));
    float cnr = xr[q] * cr[q] - xi[q] * ci[q] + i_r * ct_r - i_i * ct_i;
    float cni = xr[q] * ci[q] + xi[q] * cr[q] + i_r * ct_i + i_i * ct_r;
    float tr = ftanh(cnr), ti = ftanh(cni);
    hr[q] = o_r * tr - o_i * ti;
    hi[q] = o_r * ti + o_i * tr;
    nr[q] = cnr;
    ni[q] = cni;
  }

  *(float4v*)(out + base)                         = *(const float4v*)(hr);
  *(float4v*)(out + base + 4)                     = *(const float4v*)(hr + 4);
  *(float4v*)(out + base + 64 * 4096)             = *(const float4v*)(hi);
  *(float4v*)(out + base + 64 * 4096 + 4)         = *(const float4v*)(hi + 4);
  *(float4v*)(out + HSIZE + base)                 = *(const float4v*)(nr);
  *(float4v*)(out + HSIZE + base + 4)             = *(const float4v*)(nr + 4);
  *(float4v*)(out + HSIZE + base + 64 * 4096)     = *(const float4v*)(ni);
  *(float4v*)(out + HSIZE + base + 64 * 4096 + 4) = *(const float4v*)(ni + 4);
}

// ---------------------------------------------------------------- launch
extern "C" void kernel_launch(void* const* d_in, const int* in_sizes, int n_in,
                              void* d_out, int out_size, void* d_ws, size_t ws_size,
                              hipStream_t stream) {
  // inputs: 0 x, 1 h_prev, 2 c_prev,
  //         3 Wr_i, 4 Wi_i, 5 br_i, 6 bi_i,  7..10 f-gate (unused),
  //        11 Wr_o,12 Wi_o,13 br_o,14 bi_o, 15 Wr_c,16 Wi_c,17 br_c,18 bi_c
  const float* x = (const float*)d_in[0];
  const float* h = (const float*)d_in[1];

  char* ws = (char*)d_ws;
  short* Zp   = (short*)ws;                          // 35,684,352 B
  short* Wp   = (short*)(ws + 35684352);             //  1,769,472 B
  float* bias = (float*)(ws + 37453824);             //      1,536 B
  __hip_bfloat16* gates = (__hip_bfloat16*)(ws + 37455360); // 50,331,648 B
  // total ~87.8 MiB

  halo_zero_kernel<<<520, 256, 0, stream>>>(Zp);
  pack_z_kernel<<<4096, 256, 0, stream>>>(x, h, Zp);
  pack_w_kernel<<<3456, 256, 0, stream>>>(
      (const float*)d_in[3], (const float*)d_in[4],
      (const float*)d_in[11], (const float*)d_in[12],
      (const float*)d_in[15], (const float*)d_in[16],
      (const float*)d_in[5], (const float*)d_in[6],
      (const float*)d_in[13], (const float*)d_in[14],
      (const float*)d_in[17], (const float*)d_in[18],
      Wp, bias);
  conv_gemm<<<dim3(512, 3), 256, 0, stream>>>(Zp, Wp, bias, gates);
  epilogue_kernel<<<2048, 256, 0, stream>>>(
      gates, (const float*)d_in[0], (const float*)d_in[2],
      (float*)d_out);
}

// Round 2
// 318.150 us; speedup vs baseline: 1.0213x; 1.0213x over previous
//
#include <hip/hip_runtime.h>
#include <hip/hip_bf16.h>

// Complex ConvLSTM cell. Inputs f32, output f32 (verified R3, absmax 0.0625).
//   Zp: halo-padded packed activations, [b][y' 0..65][x' 0..65][cin 0..255] bf16
//       cin = [x lo | h lo | x hi | h hi]; halo = zeros.
//   Wp[n][tap][cin]: n = part*64+ch, parts {yr_i,yi_i,yr_o,yi_o,yr_c,yi_c};
//       yr -> [Wr ; -Wi], yi -> [Wi ; Wr].
//   conv_gemm R2: counted-vmcnt pipelined schedule (T3+T4+T5 port).
//       Double-buffered As/Bs, flat 36-step pipeline, A prefetch 1 step ahead,
//       B prefetch 3 steps ahead, s_waitcnt vmcnt(8/8/4) (never 0 in loop),
//       raw s_barrier + sched_barrier fences, setprio(1) around MFMA cluster.
//       B staging is 4 uniform loads (cols 1..64); halo cols 0/65 are zeroed
//       once in LDS (they are always zero in Zp).
//   epilogue: gate math -> h_new, c_new (f32), 8 px/thread vectorized.

typedef __attribute__((ext_vector_type(8))) short short8;
typedef __attribute__((ext_vector_type(4))) float floatx4;
typedef __attribute__((ext_vector_type(4))) float float4v;

#define MTOT   65536
#define HSIZE  8388608

__device__ __forceinline__ short f2bf(float f) {
  __hip_bfloat16 h = __float2bfloat16(f);
  return *reinterpret_cast<short*>(&h);
}

__device__ __forceinline__ float bf2f(short s) {
  unsigned u = ((unsigned)(unsigned short)s) << 16;
  return __uint_as_float(u);
}

__device__ __forceinline__ void gload16(const short* g, void* lds) {
  __builtin_amdgcn_global_load_lds(
      (__attribute__((address_space(1))) void*)(g),
      (__attribute__((address_space(3))) void*)(lds), 16, 0, 0);
}

// ---------------------------------------------------------------- halo zero
__global__ __launch_bounds__(256) void halo_zero_kernel(short* __restrict__ Zp) {
  int t = blockIdx.x * 256 + threadIdx.x;     // 520*256 = 133,120 = 4160 px * 32
  int s   = t & 31;
  int pix = t >> 5;                           // 0..4159
  int b = pix / 260;
  int r = pix - b * 260;
  int yp, xp;
  if (r < 66)       { yp = 0;               xp = r; }
  else if (r < 132) { yp = 65;              xp = r - 66; }
  else { int r2 = r - 132; yp = 1 + (r2 >> 1); xp = (r2 & 1) * 65; }
  short8 z;
#pragma unroll
  for (int q = 0; q < 8; ++q) z[q] = 0;
  *(short8*)(Zp + (((b * 66 + yp) * 66 + xp) * 256 + s * 8)) = z;
}

// ---------------------------------------------------------------- pack Z (tiled transpose)
__global__ __launch_bounds__(256) void pack_z_kernel(
    const float* __restrict__ xs, const float* __restrict__ hs,
    short* __restrict__ Zp) {
  __shared__ short tile[64 * 72];             // [xr][ch], stride 72 (16B-aligned rows)
  int bid = blockIdx.x;
  int y      = bid & 63;
  int half   = (bid >> 6) & 1;
  int srcSel = (bid >> 7) & 1;
  int b      = bid >> 8;
  const float* src = srcSel ? hs : xs;
  int chBase  = half * 64;
  int cinBase = half * 128 + srcSel * 64;
  int t = threadIdx.x;
  int x4 = t & 15, chq = t >> 4;              // 16 ch per pass
#pragma unroll
  for (int p = 0; p < 4; ++p) {
    int ch = p * 16 + chq;
    float4v f = *(const float4v*)(src + (size_t)(b * 128 + chBase + ch) * 4096 + y * 64 + x4 * 4);
#pragma unroll
    for (int e = 0; e < 4; ++e)
      tile[(x4 * 4 + e) * 72 + ch] = f2bf(f[e]);
  }
  __syncthreads();
  int x = t >> 2, seg = t & 3;
  short8 v0 = *(const short8*)(tile + x * 72 + seg * 16);
  short8 v1 = *(const short8*)(tile + x * 72 + seg * 16 + 8);
  size_t outp = ((size_t)(b * 66 + y + 1) * 66 + x + 1) * 256 + cinBase + seg * 16;
  *(short8*)(Zp + outp)     = v0;
  *(short8*)(Zp + outp + 8) = v1;
}

// ---------------------------------------------------------------- pack W + bias
__global__ __launch_bounds__(256) void pack_w_kernel(
    const float* __restrict__ Wr_i, const float* __restrict__ Wi_i,
    const float* __restrict__ Wr_o, const float* __restrict__ Wi_o,
    const float* __restrict__ Wr_c, const float* __restrict__ Wi_c,
    const float* __restrict__ br_i, const float* __restrict__ bi_i,
    const float* __restrict__ br_o, const float* __restrict__ bi_o,
    const float* __restrict__ br_c, const float* __restrict__ bi_c,
    short* __restrict__ Wp, float* __restrict__ bias) {
  int g = blockIdx.x * 256 + threadIdx.x;
  if (g >= 384 * 9 * 256) return;
  int cin = g & 255;
  int tap = (g >> 8) % 9;
  int n   = g / (256 * 9);
  int part = n >> 6, ch = n & 63;
  const float *Wr, *Wi;
  if (part < 2)      { Wr = Wr_i; Wi = Wi_i; }
  else if (part < 4) { Wr = Wr_o; Wi = Wi_o; }
  else               { Wr = Wr_c; Wi = Wi_c; }
  int im = part & 1;
  int ci = cin & 127;
  int second = cin >> 7;
  const float* src = im ? (second ? Wr : Wi) : (second ? Wi : Wr);
  float f = src[(ch * 128 + ci) * 9 + tap];
  if (!im && second) f = -f;
  Wp[(n * 9 + tap) * 256 + cin] = f2bf(f);
  if (g < 384) {
    int p2 = g >> 6, c2 = g & 63;
    const float* bs = (p2 == 0) ? br_i : (p2 == 1) ? bi_i : (p2 == 2) ? br_o
                    : (p2 == 3) ? bi_o : (p2 == 4) ? br_c : bi_c;
    bias[g] = bs[c2];
  }
}

// ---------------------------------------------------------------- implicit GEMM (pipelined)
// 128ch x 128px tile, 4 waves (each 64x64), K = 9 taps x 256 cin = 36 steps of 64.
// Step s = t*3 + dx, t = dy*4 + c0i.  A[s] in As[s&1], B[t] in Bs[t&1].
// LDS: As[2][128 rows][8 slots], Bs[2][2 r2][66 cols][8 slots]; XOR k-group swizzle.
__device__ __forceinline__ void issueA(const short* __restrict__ Wp, int n0,
                                       int ta, int dxa, short8* dst, int tid, int wv) {
  int dy  = ta >> 2;
  int c0  = (ta & 3) * 64;
  int tap = dy * 3 + dxa;
#pragma unroll
  for (int it = 0; it < 4; ++it) {
    int idx = tid + it * 256;
    int row = idx >> 3, p = idx & 7;
    int g = p ^ (row & 7);
    gload16(Wp + ((size_t)((n0 + row) * 9 + tap) * 256 + c0 + g * 8),
            (void*)(dst + (it * 256 + wv * 64)));
  }
}

__device__ __forceinline__ void issueB(const short* __restrict__ Z, int zrow0,
                                       int tb, short8* dst, int tid, int wv) {
  int dy = tb >> 2;
  int c0 = (tb & 3) * 64;
#pragma unroll
  for (int it = 0; it < 4; ++it) {
    int idx = tid + it * 256;           // 0..1023: r2 = idx>>9, col = (idx&511)>>3 + 1
    int r2  = idx >> 9;
    int rem = idx & 511;
    int col = (rem >> 3) + 1;           // cols 1..64 (0 and 65 are permanent zeros)
    int p   = rem & 7;
    int g   = p ^ (col & 7);
    int ygl = zrow0 + dy + r2;
    int idx0 = it * 256 + wv * 64;      // wave-uniform dest base
    int r2d  = idx0 >> 9;
    int rem0 = idx0 & 511;
    gload16(Z + ((size_t)(ygl * 66 + col) * 256 + c0 + g * 8),
            (void*)(dst + (r2d * 528 + 8 + rem0)));
  }
}

template<int DXI>
__device__ __forceinline__ void compute_step(const short8* __restrict__ Ac,
                                             const short8* __restrict__ Bc,
                                             floatx4 (&acc)[4][4],
                                             int wch, int r2w, int l15, int l4) {
#pragma unroll
  for (int kk = 0; kk < 2; ++kk) {
    int kg = kk * 4 + l4;
    short8 a[4], bv[4];
#pragma unroll
    for (int i = 0; i < 4; ++i) {
      int row = wch + i * 16 + l15;
      a[i] = Ac[row * 8 + (kg ^ (row & 7))];
    }
#pragma unroll
    for (int j = 0; j < 4; ++j) {
      int col = j * 16 + l15 + DXI;
      bv[j] = Bc[r2w * 528 + col * 8 + (kg ^ (col & 7))];
    }
#pragma unroll
    for (int i = 0; i < 4; ++i)
#pragma unroll
      for (int j = 0; j < 4; ++j)
        acc[i][j] = __builtin_amdgcn_mfma_f32_16x16x32_bf16(a[i], bv[j], acc[i][j], 0, 0, 0);
  }
}

__global__ __launch_bounds__(256, 2) void conv_gemm(
    const short* __restrict__ Z, const short* __restrict__ Wp,
    const float* __restrict__ bias, __hip_bfloat16* __restrict__ gates) {
  __shared__ short8 As[2][1024];   // 2 x 16 KiB
  __shared__ short8 Bs[2][1056];   // 2 x 16.5 KiB

  const int tid = threadIdx.x;
  const int wv = tid >> 6, lane = tid & 63;
  const int l15 = lane & 15, l4 = lane >> 4;
  const int m0 = blockIdx.x * 128;
  const int n0 = blockIdx.y * 128;
  const int b  = m0 >> 12;
  const int y0 = (m0 >> 6) & 63;    // even
  const int zrow0 = b * 66 + y0;
  const int wch = (wv & 1) * 64;
  const int r2w = wv >> 1;

  floatx4 acc[4][4];
#pragma unroll
  for (int i = 0; i < 4; ++i)
#pragma unroll
    for (int j = 0; j < 4; ++j)
#pragma unroll
      for (int r = 0; r < 4; ++r) acc[i][j][r] = 0.f;

  // -- prologue: zero the permanent halo columns (cols 0,65 of both B bufs),
  //    then issue A[0] -> As[0], B[0] -> Bs[0].
  if (tid < 64) {
    int buf = tid >> 5, w = tid & 31;
    int r2 = w >> 4, hi = (w >> 3) & 1, p = w & 7;
    short8 z;
#pragma unroll
    for (int q = 0; q < 8; ++q) z[q] = 0;
    Bs[buf][r2 * 528 + (hi ? 520 : 0) + p] = z;
  }
  issueA(Wp, n0, 0, 0, &As[0][0], tid, wv);
  issueB(Z, zrow0, 0, &Bs[0][0], tid, wv);
  asm volatile("s_waitcnt lgkmcnt(0)" ::: "memory");   // halo-zero ds_writes drained

#define CONV_STEP(NW, DXI, DOA, TA, DXA, ADST, DOB, TB, BDST, AC, BC)          \
  do {                                                                         \
    if (DOA) issueA(Wp, n0, (TA), (DXA), &As[ADST][0], tid, wv);               \
    if (DOB) issueB(Z, zrow0, (TB), &Bs[BDST][0], tid, wv);                    \
    asm volatile("s_waitcnt vmcnt(" #NW ")" ::: "memory");                     \
    __builtin_amdgcn_sched_barrier(0);                                         \
    __builtin_amdgcn_s_barrier();                                              \
    __builtin_amdgcn_sched_barrier(0);                                         \
    __builtin_amdgcn_s_setprio(1);                                             \
    compute_step<DXI>(&As[AC][0], &Bs[BC][0], acc, wch, r2w, l15, l4);         \
    __builtin_amdgcn_s_setprio(0);                                             \
    __builtin_amdgcn_sched_barrier(0);                                         \
    __builtin_amdgcn_s_barrier();                                              \
    __builtin_amdgcn_sched_barrier(0);                                         \
  } while (0)

  // main pipeline: t = 0..9 in pairs (parities repeat with period 6 steps)
  for (int tt = 0; tt < 5; ++tt) {
    int t0 = tt * 2;
    CONV_STEP(8, 0, true, t0,     1, 1, true,  t0 + 1, 1, 0, 0);
    CONV_STEP(8, 1, true, t0,     2, 0, false, 0,      0, 1, 0);
    CONV_STEP(4, 2, true, t0 + 1, 0, 1, false, 0,      0, 0, 0);
    CONV_STEP(8, 0, true, t0 + 1, 1, 0, true,  t0 + 2, 0, 1, 1);
    CONV_STEP(8, 1, true, t0 + 1, 2, 1, false, 0,      0, 0, 1);
    CONV_STEP(4, 2, true, t0 + 2, 0, 0, false, 0,      0, 1, 1);
  }
  // t = 10 (reads Bs[0], issues B[11] -> Bs[1])
  CONV_STEP(8, 0, true, 10, 1, 1, true,  11, 1, 0, 0);
  CONV_STEP(8, 1, true, 10, 2, 0, false, 0,  0, 1, 0);
  CONV_STEP(4, 2, true, 11, 0, 1, false, 0,  0, 0, 0);
  // t = 11 tail (reads Bs[1]; drains)
  CONV_STEP(4, 0, true, 11, 1, 0, false, 0,  0, 1, 1);
  CONV_STEP(4, 1, true, 11, 2, 1, false, 0,  0, 0, 1);
  CONV_STEP(0, 2, false, 0, 0, 0, false, 0,  0, 1, 1);
#undef CONV_STEP

#pragma unroll
  for (int i = 0; i < 4; ++i)
#pragma unroll
    for (int j = 0; j < 4; ++j)
#pragma unroll
      for (int r = 0; r < 4; ++r) {
        int ch = n0 + wch + i * 16 + l4 * 4 + r;
        int px = m0 + r2w * 64 + j * 16 + l15;
        gates[(size_t)ch * MTOT + px] = __float2bfloat16(acc[i][j][r] + bias[ch]);
      }
}

// ---------------------------------------------------------------- epilogue (f32 out)
// 8 px/thread, all accesses 8-16B/lane. 2048 blocks x 256 threads.
__device__ __forceinline__ float fsig(float v) { return 1.f / (1.f + __expf(-v)); }
__device__ __forceinline__ float ftanh(float v) {
  float e = __expf(2.f * v);
  return 1.f - 2.f / (e + 1.f);
}

__global__ __launch_bounds__(256) void epilogue_kernel(
    const __hip_bfloat16* __restrict__ gates,
    const float* __restrict__ x,
    const float* __restrict__ c_prev,
    float* __restrict__ out) {
  int t = blockIdx.x * 256 + threadIdx.x;     // 524,288 threads total
  int ch = t >> 13;                           // 0..63
  int m  = (t & 8191) << 3;                   // 8 consecutive pixels
  int b = m >> 12, sp = m & 4095;

  size_t gbase = (size_t)ch * MTOT + m;
  short8 gri = *(const short8*)((const short*)gates + gbase);
  short8 gii = *(const short8*)((const short*)gates + gbase + (size_t)64 * MTOT);
  short8 gro = *(const short8*)((const short*)gates + gbase + (size_t)128 * MTOT);
  short8 gio = *(const short8*)((const short*)gates + gbase + (size_t)192 * MTOT);
  short8 grc = *(const short8*)((const short*)gates + gbase + (size_t)256 * MTOT);
  short8 gic = *(const short8*)((const short*)gates + gbase + (size_t)320 * MTOT);

  int base = (b * 128 + ch) * 4096 + sp;
  float xr[8] __attribute__((aligned(16)));
  float xi[8] __attribute__((aligned(16)));
  float cr[8] __attribute__((aligned(16)));
  float ci[8] __attribute__((aligned(16)));
  *(float4v*)(xr)     = *(const float4v*)(x + base);
  *(float4v*)(xr + 4) = *(const float4v*)(x + base + 4);
  *(float4v*)(xi)     = *(const float4v*)(x + base + 64 * 4096);
  *(float4v*)(xi + 4) = *(const float4v*)(x + base + 64 * 4096 + 4);
  *(float4v*)(cr)     = *(const float4v*)(c_prev + base);
  *(float4v*)(cr + 4) = *(const float4v*)(c_prev + base + 4);
  *(float4v*)(ci)     = *(const float4v*)(c_prev + base + 64 * 4096);
  *(float4v*)(ci + 4) = *(const float4v*)(c_prev + base + 64 * 4096 + 4);

  float hr[8] __attribute__((aligned(16)));
  float hi[8] __attribute__((aligned(16)));
  float nr[8] __attribute__((aligned(16)));
  float ni[8] __attribute__((aligned(16)));
#pragma unroll
  for (int q = 0; q < 8; ++q) {
    float i_r = fsig(bf2f(gri[q])), i_i = fsig(bf2f(gii[q]));
    float o_r = fsig(bf2f(gro[q])), o_i = fsig(bf2f(gio[q]));
    float ct_r = ftanh(bf2f(grc[q])), ct_i = ftanh(bf2f(gic[q]));
    float cnr = xr[q] * cr[q] - xi[q] * ci[q] + i_r * ct_r - i_i * ct_i;
    float cni = xr[q] * ci[q] + xi[q] * cr[q] + i_r * ct_i + i_i * ct_r;
    float tr = ftanh(cnr), ti = ftanh(cni);
    hr[q] = o_r * tr - o_i * ti;
    hi[q] = o_r * ti + o_i * tr;
    nr[q] = cnr;
    ni[q] = cni;
  }

  *(float4v*)(out + base)                         = *(const float4v*)(hr);
  *(float4v*)(out + base + 4)                     = *(const float4v*)(hr + 4);
  *(float4v*)(out + base + 64 * 4096)             = *(const float4v*)(hi);
  *(float4v*)(out + base + 64 * 4096 + 4)         = *(const float4v*)(hi + 4);
  *(float4v*)(out + HSIZE + base)                 = *(const float4v*)(nr);
  *(float4v*)(out + HSIZE + base + 4)             = *(const float4v*)(nr + 4);
  *(float4v*)(out + HSIZE + base + 64 * 4096)     = *(const float4v*)(ni);
  *(float4v*)(out + HSIZE + base + 64 * 4096 + 4) = *(const float4v*)(ni + 4);
}

// ---------------------------------------------------------------- launch
extern "C" void kernel_launch(void* const* d_in, const int* in_sizes, int n_in,
                              void* d_out, int out_size, void* d_ws, size_t ws_size,
                              hipStream_t stream) {
  // inputs: 0 x, 1 h_prev, 2 c_prev,
  //         3 Wr_i, 4 Wi_i, 5 br_i, 6 bi_i,  7..10 f-gate (unused),
  //        11 Wr_o,12 Wi_o,13 br_o,14 bi_o, 15 Wr_c,16 Wi_c,17 br_c,18 bi_c
  const float* x = (const float*)d_in[0];
  const float* h = (const float*)d_in[1];

  char* ws = (char*)d_ws;
  short* Zp   = (short*)ws;                          // 35,684,352 B
  short* Wp   = (short*)(ws + 35684352);             //  1,769,472 B
  float* bias = (float*)(ws + 37453824);             //      1,536 B
  __hip_bfloat16* gates = (__hip_bfloat16*)(ws + 37455360); // 50,331,648 B
  // total ~87.8 MiB

  halo_zero_kernel<<<520, 256, 0, stream>>>(Zp);
  pack_z_kernel<<<4096, 256, 0, stream>>>(x, h, Zp);
  pack_w_kernel<<<3456, 256, 0, stream>>>(
      (const float*)d_in[3], (const float*)d_in[4],
      (const float*)d_in[11], (const float*)d_in[12],
      (const float*)d_in[15], (const float*)d_in[16],
      (const float*)d_in[5], (const float*)d_in[6],
      (const float*)d_in[13], (const float*)d_in[14],
      (const float*)d_in[17], (const float*)d_in[18],
      Wp, bias);
  conv_gemm<<<dim3(512, 3), 256, 0, stream>>>(Zp, Wp, bias, gates);
  epilogue_kernel<<<2048, 256, 0, stream>>>(
      gates, (const float*)d_in[0], (const float*)d_in[2],
      (float*)d_out);
}

// Round 3
// 317.877 us; speedup vs baseline: 1.0222x; 1.0009x over previous
//
#include <hip/hip_runtime.h>
#include <hip/hip_bf16.h>

// Complex ConvLSTM cell. Inputs f32, output f32 (verified, absmax 0.0625).
//   Zp: halo-padded packed activations, [b][y' 0..65][x' 0..65][cin 0..255] bf16
//       cin = [x lo | h lo | x hi | h hi]; halo = zeros.
//   Wp[n][tap][cin]: n = part*64+ch, parts {yr_i,yi_i,yr_o,yi_o,yr_c,yi_c};
//       yr -> [Wr ; -Wi], yi -> [Wi ; Wr].
//   conv_gemm R3: register-pipelined fragments (m201-style phases).
//       Each step = 2 phases of 16 MFMA; frag reads for a phase are issued
//       during the PREVIOUS phase, so MFMA clusters are pure-register.
//       One barrier per step. A prefetch 1 step, B prefetch 2 steps.
//       Counted vmcnt per 6-step-period ledger; lgkmcnt(0) before the
//       barrier drains reads of the buffer overwritten post-barrier.
//   epilogue: gate math -> h_new, c_new (f32), 8 px/thread vectorized.

typedef __attribute__((ext_vector_type(8))) short short8;
typedef __attribute__((ext_vector_type(4))) float floatx4;
typedef __attribute__((ext_vector_type(4))) float float4v;

#define MTOT   65536
#define HSIZE  8388608

__device__ __forceinline__ short f2bf(float f) {
  __hip_bfloat16 h = __float2bfloat16(f);
  return *reinterpret_cast<short*>(&h);
}

__device__ __forceinline__ float bf2f(short s) {
  unsigned u = ((unsigned)(unsigned short)s) << 16;
  return __uint_as_float(u);
}

__device__ __forceinline__ void gload16(const short* g, void* lds) {
  __builtin_amdgcn_global_load_lds(
      (__attribute__((address_space(1))) void*)(g),
      (__attribute__((address_space(3))) void*)(lds), 16, 0, 0);
}

// ---------------------------------------------------------------- halo zero
__global__ __launch_bounds__(256) void halo_zero_kernel(short* __restrict__ Zp) {
  int t = blockIdx.x * 256 + threadIdx.x;     // 520*256 = 133,120 = 4160 px * 32
  int s   = t & 31;
  int pix = t >> 5;                           // 0..4159
  int b = pix / 260;
  int r = pix - b * 260;
  int yp, xp;
  if (r < 66)       { yp = 0;               xp = r; }
  else if (r < 132) { yp = 65;              xp = r - 66; }
  else { int r2 = r - 132; yp = 1 + (r2 >> 1); xp = (r2 & 1) * 65; }
  short8 z;
#pragma unroll
  for (int q = 0; q < 8; ++q) z[q] = 0;
  *(short8*)(Zp + (((b * 66 + yp) * 66 + xp) * 256 + s * 8)) = z;
}

// ---------------------------------------------------------------- pack Z (tiled transpose)
__global__ __launch_bounds__(256) void pack_z_kernel(
    const float* __restrict__ xs, const float* __restrict__ hs,
    short* __restrict__ Zp) {
  __shared__ short tile[64 * 72];             // [xr][ch], stride 72 (16B-aligned rows)
  int bid = blockIdx.x;
  int y      = bid & 63;
  int half   = (bid >> 6) & 1;
  int srcSel = (bid >> 7) & 1;
  int b      = bid >> 8;
  const float* src = srcSel ? hs : xs;
  int chBase  = half * 64;
  int cinBase = half * 128 + srcSel * 64;
  int t = threadIdx.x;
  int x4 = t & 15, chq = t >> 4;              // 16 ch per pass
#pragma unroll
  for (int p = 0; p < 4; ++p) {
    int ch = p * 16 + chq;
    float4v f = *(const float4v*)(src + (size_t)(b * 128 + chBase + ch) * 4096 + y * 64 + x4 * 4);
#pragma unroll
    for (int e = 0; e < 4; ++e)
      tile[(x4 * 4 + e) * 72 + ch] = f2bf(f[e]);
  }
  __syncthreads();
  int x = t >> 2, seg = t & 3;
  short8 v0 = *(const short8*)(tile + x * 72 + seg * 16);
  short8 v1 = *(const short8*)(tile + x * 72 + seg * 16 + 8);
  size_t outp = ((size_t)(b * 66 + y + 1) * 66 + x + 1) * 256 + cinBase + seg * 16;
  *(short8*)(Zp + outp)     = v0;
  *(short8*)(Zp + outp + 8) = v1;
}

// ---------------------------------------------------------------- pack W + bias
__global__ __launch_bounds__(256) void pack_w_kernel(
    const float* __restrict__ Wr_i, const float* __restrict__ Wi_i,
    const float* __restrict__ Wr_o, const float* __restrict__ Wi_o,
    const float* __restrict__ Wr_c, const float* __restrict__ Wi_c,
    const float* __restrict__ br_i, const float* __restrict__ bi_i,
    const float* __restrict__ br_o, const float* __restrict__ bi_o,
    const float* __restrict__ br_c, const float* __restrict__ bi_c,
    short* __restrict__ Wp, float* __restrict__ bias) {
  int g = blockIdx.x * 256 + threadIdx.x;
  if (g >= 384 * 9 * 256) return;
  int cin = g & 255;
  int tap = (g >> 8) % 9;
  int n   = g / (256 * 9);
  int part = n >> 6, ch = n & 63;
  const float *Wr, *Wi;
  if (part < 2)      { Wr = Wr_i; Wi = Wi_i; }
  else if (part < 4) { Wr = Wr_o; Wi = Wi_o; }
  else               { Wr = Wr_c; Wi = Wi_c; }
  int im = part & 1;
  int ci = cin & 127;
  int second = cin >> 7;
  const float* src = im ? (second ? Wr : Wi) : (second ? Wi : Wr);
  float f = src[(ch * 128 + ci) * 9 + tap];
  if (!im && second) f = -f;
  Wp[(n * 9 + tap) * 256 + cin] = f2bf(f);
  if (g < 384) {
    int p2 = g >> 6, c2 = g & 63;
    const float* bs = (p2 == 0) ? br_i : (p2 == 1) ? bi_i : (p2 == 2) ? br_o
                    : (p2 == 3) ? bi_o : (p2 == 4) ? br_c : bi_c;
    bias[g] = bs[c2];
  }
}

// ---------------------------------------------------------------- implicit GEMM (reg-pipelined)
// 128ch x 128px tile, 4 waves (each 64x64), K = 9 taps x 256 cin = 36 steps of 64.
// Step s = t*3 + dx, t = dy*4 + c0i.  A[s] in As[s&1], B[t] in Bs[t&1].
// Per step: phase1 {read frags(s,kk1); MFMA frags(s,kk0)},
//           lgkmcnt(0)+vmcnt(NW)+barrier,
//           phase2 {issue A[s+2] (+B[t+1] at s%3==0); read frags(s+1,kk0);
//                   MFMA frags(s,kk1)}.
__device__ __forceinline__ void issueA(const short* __restrict__ Wp, int n0,
                                       int ta, int dxa, short8* dst, int tid, int wv) {
  int dy  = ta >> 2;
  int c0  = (ta & 3) * 64;
  int tap = dy * 3 + dxa;
#pragma unroll
  for (int it = 0; it < 4; ++it) {
    int idx = tid + it * 256;
    int row = idx >> 3, p = idx & 7;
    int g = p ^ (row & 7);
    gload16(Wp + ((size_t)((n0 + row) * 9 + tap) * 256 + c0 + g * 8),
            (void*)(dst + (it * 256 + wv * 64)));
  }
}

__device__ __forceinline__ void issueB(const short* __restrict__ Z, int zrow0,
                                       int tb, short8* dst, int tid, int wv) {
  int dy = tb >> 2;
  int c0 = (tb & 3) * 64;
#pragma unroll
  for (int it = 0; it < 4; ++it) {
    int idx = tid + it * 256;           // 0..1023: r2 = idx>>9, col = (idx&511)>>3 + 1
    int r2  = idx >> 9;
    int rem = idx & 511;
    int col = (rem >> 3) + 1;           // cols 1..64 (0 and 65 are permanent zeros)
    int p   = rem & 7;
    int g   = p ^ (col & 7);
    int ygl = zrow0 + dy + r2;
    int idx0 = it * 256 + wv * 64;      // wave-uniform dest base
    int r2d  = idx0 >> 9;
    int rem0 = idx0 & 511;
    gload16(Z + ((size_t)(ygl * 66 + col) * 256 + c0 + g * 8),
            (void*)(dst + (r2d * 528 + 8 + rem0)));
  }
}

template<int KK, int DXI>
__device__ __forceinline__ void frag_read(const short8* __restrict__ Ab,
                                          const short8* __restrict__ Bb,
                                          short8 (&a)[4], short8 (&bv)[4],
                                          int wch, int r2w, int l15, int l4) {
  int kg = KK * 4 + l4;
#pragma unroll
  for (int i = 0; i < 4; ++i) {
    int row = wch + i * 16 + l15;
    a[i] = Ab[row * 8 + (kg ^ (row & 7))];
  }
#pragma unroll
  for (int j = 0; j < 4; ++j) {
    int col = j * 16 + l15 + DXI;
    bv[j] = Bb[r2w * 528 + col * 8 + (kg ^ (col & 7))];
  }
}

__device__ __forceinline__ void mfma16(const short8 (&a)[4], const short8 (&bv)[4],
                                       floatx4 (&acc)[4][4]) {
#pragma unroll
  for (int i = 0; i < 4; ++i)
#pragma unroll
    for (int j = 0; j < 4; ++j)
      acc[i][j] = __builtin_amdgcn_mfma_f32_16x16x32_bf16(a[i], bv[j], acc[i][j], 0, 0, 0);
}

__global__ __launch_bounds__(256, 2) void conv_gemm(
    const short* __restrict__ Z, const short* __restrict__ Wp,
    const float* __restrict__ bias, __hip_bfloat16* __restrict__ gates) {
  __shared__ short8 As[2][1024];   // 2 x 16 KiB
  __shared__ short8 Bs[2][1056];   // 2 x 16.5 KiB

  const int tid = threadIdx.x;
  const int wv = tid >> 6, lane = tid & 63;
  const int l15 = lane & 15, l4 = lane >> 4;
  const int m0 = blockIdx.x * 128;
  const int n0 = blockIdx.y * 128;
  const int b  = m0 >> 12;
  const int y0 = (m0 >> 6) & 63;    // even
  const int zrow0 = b * 66 + y0;
  const int wch = (wv & 1) * 64;
  const int r2w = wv >> 1;

  floatx4 acc[4][4];
#pragma unroll
  for (int i = 0; i < 4; ++i)
#pragma unroll
    for (int j = 0; j < 4; ++j)
#pragma unroll
      for (int r = 0; r < 4; ++r) acc[i][j][r] = 0.f;

  short8 af0[4], bf0[4], af1[4], bf1[4];

  // -- prologue: zero permanent halo cols of both B bufs; stage A[0],B[0],A[1];
  //    publish A[0],B[0]; preload frags(0,kk0).
  if (tid < 64) {
    int buf = tid >> 5, w = tid & 31;
    int r2 = w >> 4, hi = (w >> 3) & 1, p = w & 7;
    short8 z;
#pragma unroll
    for (int q = 0; q < 8; ++q) z[q] = 0;
    Bs[buf][r2 * 528 + (hi ? 520 : 0) + p] = z;
  }
  issueA(Wp, n0, 0, 0, &As[0][0], tid, wv);   // A[0]
  issueB(Z, zrow0, 0, &Bs[0][0], tid, wv);    // B[0]
  issueA(Wp, n0, 0, 1, &As[1][0], tid, wv);   // A[1]
  __builtin_amdgcn_sched_barrier(0);
  asm volatile("s_waitcnt vmcnt(4) lgkmcnt(0)" ::: "memory");  // A0,B0 landed; halo done
  __builtin_amdgcn_sched_barrier(0);
  __builtin_amdgcn_s_barrier();
  __builtin_amdgcn_sched_barrier(0);
  frag_read<0, 0>(&As[0][0], &Bs[0][0], af0, bf0, wch, r2w, l15, l4);

  // STEP: phase1 reads (s,kk1) + MFMA (s,kk0); mid waitcnt+barrier;
  //       phase2 issues gloads + reads (s+1,kk0) + MFMA (s,kk1).
#define STEP(NW, DOA, TOA, DXA, ABUF, DOB, TOB, BISS, TBUF, TBN, ANXT, DXS, DXN, DON) \
  do {                                                                         \
    frag_read<1, DXS>(&As[ABUF][0], &Bs[TBUF][0], af1, bf1, wch, r2w, l15, l4);\
    __builtin_amdgcn_s_setprio(1);                                             \
    mfma16(af0, bf0, acc);                                                     \
    __builtin_amdgcn_s_setprio(0);                                             \
    __builtin_amdgcn_sched_barrier(0);                                         \
    asm volatile("s_waitcnt vmcnt(" #NW ") lgkmcnt(0)" ::: "memory");          \
    __builtin_amdgcn_sched_barrier(0);                                         \
    __builtin_amdgcn_s_barrier();                                              \
    __builtin_amdgcn_sched_barrier(0);                                         \
    if (DOA) issueA(Wp, n0, t0 + (TOA), (DXA), &As[ABUF][0], tid, wv);         \
    if (DOB) issueB(Z, zrow0, t0 + (TOB), &Bs[BISS][0], tid, wv);              \
    if (DON) frag_read<0, DXN>(&As[ANXT][0], &Bs[TBN][0], af0, bf0,            \
                               wch, r2w, l15, l4);                             \
    __builtin_amdgcn_s_setprio(1);                                             \
    mfma16(af1, bf1, acc);                                                     \
    __builtin_amdgcn_s_setprio(0);                                             \
  } while (0)

  // steady: u = 0..4 (steps 0..29), t0 = 2u
  for (int u = 0; u < 5; ++u) {
    int t0 = u * 2;
    //   NW DOA TOA DXA ABUF DOB TOB BISS TBUF TBN ANXT DXS DXN DON
    STEP(0,  1,  0,  2,  0,   1,  1,  1,   0,   0,  1,   0,  1,  1);  // r=0
    STEP(4,  1,  1,  0,  1,   0,  0,  0,   0,   0,  0,   1,  2,  1);  // r=1
    STEP(0,  1,  1,  1,  0,   0,  0,  0,   0,   1,  1,   2,  0,  1);  // r=2
    STEP(0,  1,  1,  2,  1,   1,  2,  0,   1,   1,  0,   0,  1,  1);  // r=3
    STEP(4,  1,  2,  0,  0,   0,  0,  0,   1,   1,  1,   1,  2,  1);  // r=4
    STEP(0,  1,  2,  1,  1,   0,  0,  0,   1,   0,  0,   2,  0,  1);  // r=5
  }
  // tail: u = 5 (steps 30..35), t0 = 10; B[11] issued at r=0; no B[12]; no A[36+]
  {
    int t0 = 10;
    STEP(0,  1,  0,  2,  0,   1,  1,  1,   0,   0,  1,   0,  1,  1);  // s=30
    STEP(4,  1,  1,  0,  1,   0,  0,  0,   0,   0,  0,   1,  2,  1);  // s=31
    STEP(0,  1,  1,  1,  0,   0,  0,  0,   0,   1,  1,   2,  0,  1);  // s=32
    STEP(0,  1,  1,  2,  1,   0,  0,  0,   1,   1,  0,   0,  1,  1);  // s=33
    STEP(0,  0,  0,  0,  0,   0,  0,  0,   1,   1,  1,   1,  2,  1);  // s=34 (drain A[35])
    STEP(0,  0,  0,  0,  1,   0,  0,  0,   1,   0,  0,   2,  0,  0);  // s=35
  }
#undef STEP

#pragma unroll
  for (int i = 0; i < 4; ++i)
#pragma unroll
    for (int j = 0; j < 4; ++j)
#pragma unroll
      for (int r = 0; r < 4; ++r) {
        int ch = n0 + wch + i * 16 + l4 * 4 + r;
        int px = m0 + r2w * 64 + j * 16 + l15;
        gates[(size_t)ch * MTOT + px] = __float2bfloat16(acc[i][j][r] + bias[ch]);
      }
}

// ---------------------------------------------------------------- epilogue (f32 out)
// 8 px/thread, all accesses 8-16B/lane. 2048 blocks x 256 threads.
__device__ __forceinline__ float fsig(float v) { return 1.f / (1.f + __expf(-v)); }
__device__ __forceinline__ float ftanh(float v) {
  float e = __expf(2.f * v);
  return 1.f - 2.f / (e + 1.f);
}

__global__ __launch_bounds__(256) void epilogue_kernel(
    const __hip_bfloat16* __restrict__ gates,
    const float* __restrict__ x,
    const float* __restrict__ c_prev,
    float* __restrict__ out) {
  int t = blockIdx.x * 256 + threadIdx.x;     // 524,288 threads total
  int ch = t >> 13;                           // 0..63
  int m  = (t & 8191) << 3;                   // 8 consecutive pixels
  int b = m >> 12, sp = m & 4095;

  size_t gbase = (size_t)ch * MTOT + m;
  short8 gri = *(const short8*)((const short*)gates + gbase);
  short8 gii = *(const short8*)((const short*)gates + gbase + (size_t)64 * MTOT);
  short8 gro = *(const short8*)((const short*)gates + gbase + (size_t)128 * MTOT);
  short8 gio = *(const short8*)((const short*)gates + gbase + (size_t)192 * MTOT);
  short8 grc = *(const short8*)((const short*)gates + gbase + (size_t)256 * MTOT);
  short8 gic = *(const short8*)((const short*)gates + gbase + (size_t)320 * MTOT);

  int base = (b * 128 + ch) * 4096 + sp;
  float xr[8] __attribute__((aligned(16)));
  float xi[8] __attribute__((aligned(16)));
  float cr[8] __attribute__((aligned(16)));
  float ci[8] __attribute__((aligned(16)));
  *(float4v*)(xr)     = *(const float4v*)(x + base);
  *(float4v*)(xr + 4) = *(const float4v*)(x + base + 4);
  *(float4v*)(xi)     = *(const float4v*)(x + base + 64 * 4096);
  *(float4v*)(xi + 4) = *(const float4v*)(x + base + 64 * 4096 + 4);
  *(float4v*)(cr)     = *(const float4v*)(c_prev + base);
  *(float4v*)(cr + 4) = *(const float4v*)(c_prev + base + 4);
  *(float4v*)(ci)     = *(const float4v*)(c_prev + base + 64 * 4096);
  *(float4v*)(ci + 4) = *(const float4v*)(c_prev + base + 64 * 4096 + 4);

  float hr[8] __attribute__((aligned(16)));
  float hi[8] __attribute__((aligned(16)));
  float nr[8] __attribute__((aligned(16)));
  float ni[8] __attribute__((aligned(16)));
#pragma unroll
  for (int q = 0; q < 8; ++q) {
    float i_r = fsig(bf2f(gri[q])), i_i = fsig(bf2f(gii[q]));
    float o_r = fsig(bf2f(gro[q])), o_i = fsig(bf2f(gio[q]));
    float ct_r = ftanh(bf2f(grc[q])), ct_i = ftanh(bf2f(gic[q]));
    float cnr = xr[q] * cr[q] - xi[q] * ci[q] + i_r * ct_r - i_i * ct_i;
    float cni = xr[q] * ci[q] + xi[q] * cr[q] + i_r * ct_i + i_i * ct_r;
    float tr = ftanh(cnr), ti = ftanh(cni);
    hr[q] = o_r * tr - o_i * ti;
    hi[q] = o_r * ti + o_i * tr;
    nr[q] = cnr;
    ni[q] = cni;
  }

  *(float4v*)(out + base)                         = *(const float4v*)(hr);
  *(float4v*)(out + base + 4)                     = *(const float4v*)(hr + 4);
  *(float4v*)(out + base + 64 * 4096)             = *(const float4v*)(hi);
  *(float4v*)(out + base + 64 * 4096 + 4)         = *(const float4v*)(hi + 4);
  *(float4v*)(out + HSIZE + base)                 = *(const float4v*)(nr);
  *(float4v*)(out + HSIZE + base + 4)             = *(const float4v*)(nr + 4);
  *(float4v*)(out + HSIZE + base + 64 * 4096)     = *(const float4v*)(ni);
  *(float4v*)(out + HSIZE + base + 64 * 4096 + 4) = *(const float4v*)(ni + 4);
}

// ---------------------------------------------------------------- launch
extern "C" void kernel_launch(void* const* d_in, const int* in_sizes, int n_in,
                              void* d_out, int out_size, void* d_ws, size_t ws_size,
                              hipStream_t stream) {
  // inputs: 0 x, 1 h_prev, 2 c_prev,
  //         3 Wr_i, 4 Wi_i, 5 br_i, 6 bi_i,  7..10 f-gate (unused),
  //        11 Wr_o,12 Wi_o,13 br_o,14 bi_o, 15 Wr_c,16 Wi_c,17 br_c,18 bi_c
  const float* x = (const float*)d_in[0];
  const float* h = (const float*)d_in[1];

  char* ws = (char*)d_ws;
  short* Zp   = (short*)ws;                          // 35,684,352 B
  short* Wp   = (short*)(ws + 35684352);             //  1,769,472 B
  float* bias = (float*)(ws + 37453824);             //      1,536 B
  __hip_bfloat16* gates = (__hip_bfloat16*)(ws + 37455360); // 50,331,648 B
  // total ~87.8 MiB

  halo_zero_kernel<<<520, 256, 0, stream>>>(Zp);
  pack_z_kernel<<<4096, 256, 0, stream>>>(x, h, Zp);
  pack_w_kernel<<<3456, 256, 0, stream>>>(
      (const float*)d_in[3], (const float*)d_in[4],
      (const float*)d_in[11], (const float*)d_in[12],
      (const float*)d_in[15], (const float*)d_in[16],
      (const float*)d_in[5], (const float*)d_in[6],
      (const float*)d_in[13], (const float*)d_in[14],
      (const float*)d_in[17], (const float*)d_in[18],
      Wp, bias);
  conv_gemm<<<dim3(512, 3), 256, 0, stream>>>(Zp, Wp, bias, gates);
  epilogue_kernel<<<2048, 256, 0, stream>>>(
      gates, (const float*)d_in[0], (const float*)d_in[2],
      (float*)d_out);
}